// Round 3
// baseline (239.222 us; speedup 1.0000x reference)
//
#include <hip/hip_runtime.h>
#include <string.h>

#define NN 30000
#define NE 480000
#define CAP 96
#define SCALE 0.0625f

typedef __attribute__((ext_vector_type(8))) _Float16 f16x8;
typedef __attribute__((ext_vector_type(4))) float f32x4;
typedef __attribute__((ext_vector_type(4))) int i32x4;
typedef __attribute__((ext_vector_type(2))) unsigned int u32x2;

__device__ __forceinline__ unsigned short f2h(float f) {
    _Float16 h = (_Float16)f;
    unsigned short u;
    memcpy(&u, &h, 2);
    return u;
}

__device__ __forceinline__ void gload16(const void* g, void* l) {
    __builtin_amdgcn_global_load_lds(
        (const __attribute__((address_space(1))) unsigned int*)g,
        (__attribute__((address_space(3))) unsigned int*)l, 16, 0, 0);
}

// ---------------- LayerNorm -> fp16 x ----------------
__global__ __launch_bounds__(256) void ln_kernel(const float* __restrict__ s,
                                                 const float* __restrict__ gamma,
                                                 const float* __restrict__ beta,
                                                 unsigned short* __restrict__ xh) {
    const int n = blockIdx.x;
    const int c = threadIdx.x;
    float v = s[n * 256 + c];
    float sum = v, sq = v * v;
    for (int o = 32; o; o >>= 1) {
        sum += __shfl_down(sum, o, 64);
        sq  += __shfl_down(sq,  o, 64);
    }
    __shared__ float ssum[4], ssq[4];
    const int wave = c >> 6, lane = c & 63;
    if (lane == 0) { ssum[wave] = sum; ssq[wave] = sq; }
    __syncthreads();
    float ts = ssum[0] + ssum[1] + ssum[2] + ssum[3];
    float tq = ssq[0]  + ssq[1]  + ssq[2]  + ssq[3];
    float mu  = ts * (1.0f / 256.0f);
    float var = tq * (1.0f / 256.0f) - mu * mu;
    float x = (v - mu) * rsqrtf(var + 1e-5f) * gamma[c] + beta[c];
    xh[n * 256 + c] = f2h(x);
}

// ---------------- Wqkv [256,768] f32 -> WT [768,256] fp16 ----------------
__global__ __launch_bounds__(256) void wt_kernel(const float* __restrict__ W,
                                                 unsigned short* __restrict__ WT) {
    const int idx = blockIdx.x * 256 + threadIdx.x;
    if (idx < 768 * 256) {
        const int n = idx >> 8;
        const int k = idx & 255;
        WT[idx] = f2h(W[k * 768 + n]);
    }
}

__global__ __launch_bounds__(256) void zero_kernel(int* __restrict__ p, int n) {
    const int i = blockIdx.x * 256 + threadIdx.x;
    if (i < n) p[i] = 0;
}

__global__ __launch_bounds__(256) void scatter_kernel(const int* __restrict__ src,
                                                      const int* __restrict__ dst,
                                                      int* __restrict__ cursor,
                                                      int* __restrict__ col) {
    const int e = blockIdx.x * 256 + threadIdx.x;
    if (e < NE) {
        const int d = dst[e];
        const int slot = atomicAdd(&cursor[d], 1);
        if (slot < CAP) col[d * CAP + slot] = src[e];
    }
}

// ---------------- GEMM: m97-style, global_load_lds staging, LDS-transposed epilogue ----
#define BM 128
#define BN 128
#define BK 32
#define CSTRIDE 136  // epilogue row stride in ushorts (272 B, 16B-aligned rows)

__global__ __launch_bounds__(256) void gemm_kernel(const unsigned short* __restrict__ A,   // [30000,256] fp16
                                                   const unsigned short* __restrict__ B,   // [768,256]   fp16 (n-major)
                                                   unsigned short* __restrict__ qb,
                                                   unsigned short* __restrict__ kb,
                                                   unsigned short* __restrict__ vb) {
    __shared__ unsigned short smem[BM * CSTRIDE];   // 34816 B; reused: As(4096) | Bs(4096) then Ct
    unsigned short* As = smem;          // [128][32] ushorts, 64 B rows
    unsigned short* Bs = smem + 4096;

    const int tid  = threadIdx.x;
    const int lane = tid & 63;
    const int wave = tid >> 6;
    const int bm = blockIdx.x * BM;
    const int by = blockIdx.y;                  // 0..5
    const int bn = by * BN;
    const int wm = (wave & 1) * 64;
    const int wn = (wave >> 1) * 64;
    const int l16  = lane & 15;
    const int quad = lane >> 4;

    // staging geometry: lane l covers row (wave*16 + l>>2), 16B chunk (l&3)
    const int srow = wave * 16 + (lane >> 2);
    const int ko   = (lane & 3) * 8;            // ushort offset in K

    int gmA0 = bm + srow;       if (gmA0 >= NN) gmA0 = NN - 1;
    int gmA1 = bm + srow + 64;  if (gmA1 >= NN) gmA1 = NN - 1;
    const int gnB0 = bn + srow;
    const int gnB1 = bn + srow + 64;

    f32x4 acc[4][4] = {};

    for (int kt = 0; kt < 256; kt += BK) {
        gload16(A + (size_t)gmA0 * 256 + kt + ko, &As[(wave * 16) * 32]);
        gload16(A + (size_t)gmA1 * 256 + kt + ko, &As[(64 + wave * 16) * 32]);
        gload16(B + (size_t)gnB0 * 256 + kt + ko, &Bs[(wave * 16) * 32]);
        gload16(B + (size_t)gnB1 * 256 + kt + ko, &Bs[(64 + wave * 16) * 32]);
        __syncthreads();

        f16x8 af[4], bfr[4];
        #pragma unroll
        for (int i = 0; i < 4; i++)
            af[i]  = *(const f16x8*)(&As[(wm + i * 16 + l16) * 32 + quad * 8]);
        #pragma unroll
        for (int j = 0; j < 4; j++)
            bfr[j] = *(const f16x8*)(&Bs[(wn + j * 16 + l16) * 32 + quad * 8]);
        #pragma unroll
        for (int i = 0; i < 4; i++)
            #pragma unroll
            for (int j = 0; j < 4; j++)
                acc[i][j] = __builtin_amdgcn_mfma_f32_16x16x32_f16(af[i], bfr[j], acc[i][j], 0, 0, 0);
        __syncthreads();
    }

    // ---- epilogue: transpose through LDS, vectorized fp16 stores ----
    #pragma unroll
    for (int i = 0; i < 4; i++)
        #pragma unroll
        for (int j = 0; j < 4; j++)
            #pragma unroll
            for (int r = 0; r < 4; r++)
                smem[(wm + i * 16 + quad * 4 + r) * CSTRIDE + wn + j * 16 + l16] =
                    f2h(acc[i][j][r]);
    __syncthreads();

    const int sector  = by >> 1;                 // 0=q,1=k,2=v
    const int colhalf = (by & 1) * 128;
    unsigned short* dbuf = (sector == 0) ? qb : ((sector == 1) ? kb : vb);
    const int row  = tid >> 1;                   // 0..127
    const int cseg = (tid & 1) * 64;             // 64 ushorts each
    const int grow = bm + row;
    if (grow < NN) {
        #pragma unroll
        for (int k = 0; k < 8; k++) {
            i32x4 val = *(const i32x4*)(&smem[row * CSTRIDE + cseg + k * 8]);
            *(i32x4*)(dbuf + (size_t)grow * 256 + colhalf + cseg + k * 8) = val;
        }
    }
}

// ---------------- per-dst softmax + aggregate: wave-per-node ----------------
__global__ __launch_bounds__(256) void edge_kernel(const unsigned short* __restrict__ qb,
                                                   const unsigned short* __restrict__ kb,
                                                   const unsigned short* __restrict__ vb,
                                                   const int* __restrict__ cursor,
                                                   const int* __restrict__ col,
                                                   float* __restrict__ out) {
    const int wave = threadIdx.x >> 6;
    const int lane = threadIdx.x & 63;
    const int n = blockIdx.x * 4 + wave;        // NN divisible by 4

    __shared__ int sidx[4][CAP];
    int deg = cursor[n];
    if (deg > CAP) deg = CAP;
    if (lane < deg)      sidx[wave][lane]      = col[n * CAP + lane];
    if (64 + lane < deg) sidx[wave][64 + lane] = col[n * CAP + 64 + lane];
    // wave-local write->read; compiler inserts lgkmcnt wait, no barrier needed

    union QV { u32x2 u; _Float16 h[4]; };
    QV kw;
    kw.u = *(const u32x2*)(kb + (size_t)n * 256 + 4 * lane);
    float kk[4];
    #pragma unroll
    for (int c = 0; c < 4; c++) kk[c] = (float)kw.h[c] * SCALE;

    float z[4] = {0.f, 0.f, 0.f, 0.f};
    float ac[4] = {0.f, 0.f, 0.f, 0.f};

    QV qc, vc, qn, vn;
    if (deg > 0) {
        const size_t s = (size_t)sidx[wave][0];
        qc.u = *(const u32x2*)(qb + s * 256 + 4 * lane);
        vc.u = *(const u32x2*)(vb + s * 256 + 4 * lane);
    }
    for (int i = 0; i < deg; ++i) {
        if (i + 1 < deg) {
            const size_t s = (size_t)sidx[wave][i + 1];
            qn.u = *(const u32x2*)(qb + s * 256 + 4 * lane);
            vn.u = *(const u32x2*)(vb + s * 256 + 4 * lane);
        }
        #pragma unroll
        for (int c = 0; c < 4; c++) {
            const float w = __expf((float)qc.h[c] * kk[c]);
            z[c] += w;
            ac[c] += w * (float)vc.h[c];
        }
        qc = qn;
        vc = vn;
    }

    f32x4 o;
    #pragma unroll
    for (int c = 0; c < 4; c++) o[c] = (deg > 0) ? (ac[c] / z[c]) : 0.0f;
    *(f32x4*)(out + (size_t)n * 256 + 4 * lane) = o;
}

extern "C" void kernel_launch(void* const* d_in, const int* in_sizes, int n_in,
                              void* d_out, int out_size, void* d_ws, size_t ws_size,
                              hipStream_t stream) {
    const float* s     = (const float*)d_in[0];
    const float* Wqkv  = (const float*)d_in[1];
    const float* gamma = (const float*)d_in[2];
    const float* beta  = (const float*)d_in[3];
    const int*   src   = (const int*)d_in[4];
    const int*   dst   = (const int*)d_in[5];
    float* out = (float*)d_out;

    char* ws = (char*)d_ws;
    unsigned short* xh  = (unsigned short*)(ws);                    // 15,360,000 B
    unsigned short* WT  = (unsigned short*)(ws + 15360000);         //    393,216 B
    unsigned short* qbf = (unsigned short*)(ws + 15753216);         // 15,360,000 B
    unsigned short* kbf = (unsigned short*)(ws + 31113216);         // 15,360,000 B
    unsigned short* vbf = (unsigned short*)(ws + 46473216);         // 15,360,000 B
    int*            cur = (int*)(ws + 61833216);                    //    120,000 B
    int*            col = (int*)(ws + 61953216);                    // 11,520,000 B (~73.5 MB)

    ln_kernel<<<NN, 256, 0, stream>>>(s, gamma, beta, xh);
    wt_kernel<<<(768 * 256 + 255) / 256, 256, 0, stream>>>(Wqkv, WT);
    zero_kernel<<<(NN + 255) / 256, 256, 0, stream>>>(cur, NN);
    scatter_kernel<<<(NE + 255) / 256, 256, 0, stream>>>(src, dst, cur, col);
    gemm_kernel<<<dim3((NN + BM - 1) / BM, 6), 256, 0, stream>>>(xh, WT, qbf, kbf, vbf);
    edge_kernel<<<NN / 4, 256, 0, stream>>>(qbf, kbf, vbf, cur, col, out);
}